// Round 1
// baseline (164.738 us; speedup 1.0000x reference)
//
#include <hip/hip_runtime.h>
#include <hip/hip_bf16.h>

#define Bb 16
#define Ll 256
#define EMBd 128
#define Hh 10
#define G4 40
#define ENTN 30
#define ENCd 84

__device__ __forceinline__ float ex2(float x){ return __builtin_amdgcn_exp2f(x); }
__device__ __forceinline__ float frcp(float x){ return __builtin_amdgcn_rcpf(x); }
#define LOG2E 1.4426950408889634f
__device__ __forceinline__ float sigf(float x){ return frcp(1.f + ex2(-LOG2E*x)); }
__device__ __forceinline__ float tanhf_fast(float x){ return 1.f - 2.f*frcp(1.f + ex2(2.f*LOG2E*x)); }

// K0: W1 = Wuv[:64]@Wr, W2 = Wuv[64:]@Wr, biasp = buv@Wr + br
__global__ __launch_bounds__(256) void k0_weights(
    const float* __restrict__ Wuv, const float* __restrict__ buv,
    const float* __restrict__ Wr,  const float* __restrict__ br,
    float* __restrict__ W1, float* __restrict__ W2, float* __restrict__ biasp) {
  int idx = blockIdx.x*256 + threadIdx.x;
  if (idx < 4096) {
    int r = idx >> 6, k = idx & 63;
    float acc = 0.f;
    #pragma unroll 8
    for (int s = 0; s < 64; ++s) acc = fmaf(Wuv[r*64+s], Wr[s*64+k], acc);
    W1[idx] = acc;
  } else if (idx < 8192) {
    int j = idx - 4096; int r = j >> 6, k = j & 63;
    float acc = 0.f;
    #pragma unroll 8
    for (int s = 0; s < 64; ++s) acc = fmaf(Wuv[(64+r)*64+s], Wr[s*64+k], acc);
    W2[j] = acc;
  } else if (idx < 8256) {
    int k = idx - 8192;
    float acc = br[k];
    #pragma unroll 8
    for (int s = 0; s < 64; ++s) acc = fmaf(buv[s], Wr[s*64+k], acc);
    biasp[k] = acc;
  }
}

// K1: embed = [char_table[cid], word_table[wid]]; gx = embed@Wx + b, both dirs.
// gx_f laid out [t][b][40]; gx_b laid out [t'][b][40] with t' = L-1-t (pre-reversed).
__global__ __launch_bounds__(128) void k1_embed_gates(
    const int* __restrict__ char_ids, const int* __restrict__ word_ids,
    const float* __restrict__ char_table, const float* __restrict__ word_table,
    const float* __restrict__ Wx_f, const float* __restrict__ b_f,
    const float* __restrict__ Wx_b, const float* __restrict__ b_b,
    float* __restrict__ gx_f, float* __restrict__ gx_b) {
  int tok = blockIdx.x;             // b*L + t
  int b = tok >> 8, t = tok & 255;
  int tid = threadIdx.x;
  __shared__ float e[256];
  int cid = char_ids[tok];
  int wid = word_ids[tok];
  e[tid]       = char_table[cid*EMBd + tid];
  e[tid + 128] = word_table[wid*EMBd + tid];
  __syncthreads();
  if (tid < G4) {
    float acc = b_f[tid];
    #pragma unroll 8
    for (int k = 0; k < 256; ++k) acc = fmaf(e[k], Wx_f[k*G4 + tid], acc);
    gx_f[(t*Bb + b)*G4 + tid] = acc;
  } else if (tid >= 64 && tid < 64 + G4) {
    int u = tid - 64;
    float acc = b_b[u];
    #pragma unroll 8
    for (int k = 0; k < 256; ++k) acc = fmaf(e[k], Wx_b[k*G4 + u], acc);
    gx_b[((Ll-1-t)*Bb + b)*G4 + u] = acc;
  }
}

// K2: one wave per (batch, direction). Lane j<10 computes its 4 gates; h broadcast by readlane.
__global__ __launch_bounds__(64) void k2_lstm(
    const int* __restrict__ char_ids,
    const float* __restrict__ gx_f, const float* __restrict__ gx_b,
    const float* __restrict__ Wh_f, const float* __restrict__ Wh_b,
    float* __restrict__ sent) {
  int bid = blockIdx.x;
  int dir = bid & 1, b = bid >> 1;
  int lane = threadIdx.x;
  int j = lane < Hh ? lane : 0;          // clamp so idle lanes stay in-bounds
  const float* gx = dir ? gx_b : gx_f;
  const float* Wh = dir ? Wh_b : Wh_f;
  float wA[Hh], wB[Hh], wC[Hh], wD[Hh];
  #pragma unroll
  for (int k = 0; k < Hh; ++k) {
    wA[k] = Wh[k*G4 + j];
    wB[k] = Wh[k*G4 + j + Hh];
    wC[k] = Wh[k*G4 + j + 2*Hh];
    wD[k] = Wh[k*G4 + j + 3*Hh];
  }
  float hbc[Hh];
  #pragma unroll
  for (int k = 0; k < Hh; ++k) hbc[k] = 0.f;
  float c = 0.f, h = 0.f;
  const float* gp = gx + b*G4 + j;
  // prefetch step 0
  float nI = gp[0], nF = gp[Hh], nG = gp[2*Hh], nO = gp[3*Hh];
  int ncid = char_ids[b*Ll + (dir ? Ll-1 : 0)];
  for (int t = 0; t < Ll; ++t) {
    float gI = nI, gF = nF, gG = nG, gO = nO;
    int cid = ncid;
    if (t < Ll-1) {
      const float* gn = gp + (size_t)(t+1)*Bb*G4;
      nI = gn[0]; nF = gn[Hh]; nG = gn[2*Hh]; nO = gn[3*Hh];
      ncid = char_ids[b*Ll + (dir ? (Ll-2-t) : (t+1))];
    }
    float zi = gI, zf = gF, zg = gG, zo = gO;
    #pragma unroll
    for (int k = 0; k < Hh; ++k) {
      zi = fmaf(hbc[k], wA[k], zi);
      zf = fmaf(hbc[k], wB[k], zf);
      zg = fmaf(hbc[k], wC[k], zg);
      zo = fmaf(hbc[k], wD[k], zo);
    }
    float ig = sigf(zi), fg = sigf(zf), og = sigf(zo);
    float gg = tanhf_fast(zg);
    float cn = fmaf(fg, c, ig*gg);
    float hn = og * tanhf_fast(cn);
    bool m = (cid != 0);
    c = m ? cn : c;
    h = m ? hn : h;
    int t_orig = dir ? (Ll-1-t) : t;
    if (lane < Hh) sent[(b*Ll + t_orig)*20 + dir*Hh + lane] = h;
    #pragma unroll
    for (int k = 0; k < Hh; ++k)
      hbc[k] = __uint_as_float(__builtin_amdgcn_readlane(__float_as_uint(h), k));
  }
}

// K3: per-token head: entity_logits, su/sv, A' = su@W1, C' = sv@W2
__global__ __launch_bounds__(64) void k3_token(
    const int* __restrict__ entity_ids,
    const float* __restrict__ ent_table,
    const float* __restrict__ sent,
    const float* __restrict__ We, const float* __restrict__ be,
    const float* __restrict__ Wu, const float* __restrict__ bu,
    const float* __restrict__ Wv, const float* __restrict__ bv,
    const float* __restrict__ W1, const float* __restrict__ W2,
    float* __restrict__ ent_logits, float* __restrict__ Ap, float* __restrict__ Cp) {
  int tok = blockIdx.x;
  int tid = threadIdx.x;
  __shared__ float enc[ENCd];
  __shared__ float su[64], sv[64];
  int eid = entity_ids[tok];
  if (tid < 20) enc[tid] = sent[tok*20 + tid];
  if (tid < ENCd - 20) enc[20 + tid] = ent_table[eid*64 + tid];
  __syncthreads();
  float a = bu[tid], v = bv[tid];
  #pragma unroll 4
  for (int k = 0; k < ENCd; ++k) {
    float ek = enc[k];
    a = fmaf(ek, Wu[k*64 + tid], a);
    v = fmaf(ek, Wv[k*64 + tid], v);
  }
  a = fmaxf(a, 0.f); v = fmaxf(v, 0.f);
  su[tid] = a; sv[tid] = v;
  if (tid < ENTN) {
    float el = be[tid];
    #pragma unroll
    for (int k = 0; k < 20; ++k) el = fmaf(enc[k], We[k*ENTN + tid], el);
    ent_logits[tok*ENTN + tid] = el;
  }
  __syncthreads();
  float accA = 0.f, accC = 0.f;
  #pragma unroll 8
  for (int r = 0; r < 64; ++r) {
    accA = fmaf(su[r], W1[r*64 + tid], accA);
    accC = fmaf(sv[r], W2[r*64 + tid], accC);
  }
  Ap[tok*64 + tid] = accA;
  Cp[tok*64 + tid] = accC;
}

// K4: rel_logits[b,i,j,:] = softmax_k(A'[b,j,k] + C'[b,i,k] + biasp[k])
// 16 rows per 256-thread block; 16 lanes x float4 per row.
__global__ __launch_bounds__(256) void k4_rel(
    const float* __restrict__ Ap, const float* __restrict__ Cp,
    const float* __restrict__ biasp, float* __restrict__ rel) {
  int tid = threadIdx.x;
  int rowLocal = tid >> 4;
  int k4 = tid & 15;
  int row = blockIdx.x*16 + rowLocal;      // b*L*L + i*L + j, < 2^20
  int b  = row >> 16;
  int ij = row & 65535;
  int i  = ij >> 8, j = ij & 255;
  const float4 a4 = *(const float4*)(Ap + ((size_t)(b*Ll + j))*64 + k4*4);
  const float4 c4 = *(const float4*)(Cp + ((size_t)(b*Ll + i))*64 + k4*4);
  const float4 bb = *(const float4*)(biasp + k4*4);
  float x0 = a4.x + c4.x + bb.x;
  float x1 = a4.y + c4.y + bb.y;
  float x2 = a4.z + c4.z + bb.z;
  float x3 = a4.w + c4.w + bb.w;
  float m = fmaxf(fmaxf(x0, x1), fmaxf(x2, x3));
  #pragma unroll
  for (int s = 1; s < 16; s <<= 1) m = fmaxf(m, __shfl_xor(m, s));
  float e0 = ex2(LOG2E*(x0 - m));
  float e1 = ex2(LOG2E*(x1 - m));
  float e2 = ex2(LOG2E*(x2 - m));
  float e3 = ex2(LOG2E*(x3 - m));
  float ssum = (e0 + e1) + (e2 + e3);
  #pragma unroll
  for (int s = 1; s < 16; s <<= 1) ssum += __shfl_xor(ssum, s);
  float rs = frcp(ssum);
  float4 o; o.x = e0*rs; o.y = e1*rs; o.z = e2*rs; o.w = e3*rs;
  *(float4*)(rel + (size_t)row*64 + k4*4) = o;
}

extern "C" void kernel_launch(void* const* d_in, const int* in_sizes, int n_in,
                              void* d_out, int out_size, void* d_ws, size_t ws_size,
                              hipStream_t stream) {
  const int*   char_ids   = (const int*)  d_in[0];
  const int*   word_ids   = (const int*)  d_in[1];
  const int*   entity_ids = (const int*)  d_in[2];
  const float* char_table = (const float*)d_in[3];
  const float* word_table = (const float*)d_in[4];
  const float* ent_table  = (const float*)d_in[5];
  const float* Wx_f = (const float*)d_in[6];
  const float* Wh_f = (const float*)d_in[7];
  const float* b_f  = (const float*)d_in[8];
  const float* Wx_b = (const float*)d_in[9];
  const float* Wh_b = (const float*)d_in[10];
  const float* b_b  = (const float*)d_in[11];
  const float* We = (const float*)d_in[12];
  const float* be = (const float*)d_in[13];
  const float* Wu = (const float*)d_in[14];
  const float* bu = (const float*)d_in[15];
  const float* Wv = (const float*)d_in[16];
  const float* bv = (const float*)d_in[17];
  const float* Wuv = (const float*)d_in[18];
  const float* buv = (const float*)d_in[19];
  const float* Wr  = (const float*)d_in[20];
  const float* br  = (const float*)d_in[21];

  float* ws   = (float*)d_ws;
  float* gx_f = ws;                  // 256*16*40 = 163840
  float* gx_b = gx_f + 163840;       // 163840
  float* sent = gx_b + 163840;       // 16*256*20 = 81920
  float* W1   = sent + 81920;        // 4096
  float* W2   = W1 + 4096;           // 4096
  float* biasp= W2 + 4096;           // 64
  float* Ap   = biasp + 64;          // 16*256*64 = 262144
  float* Cp   = Ap + 262144;         // 262144

  float* out = (float*)d_out;
  float* ent_logits = out;           // 16*256*30 = 122880
  float* rel = out + 122880;         // 16*256*256*64

  hipLaunchKernelGGL(k0_weights, dim3(33), dim3(256), 0, stream,
                     Wuv, buv, Wr, br, W1, W2, biasp);
  hipLaunchKernelGGL(k1_embed_gates, dim3(4096), dim3(128), 0, stream,
                     char_ids, word_ids, char_table, word_table,
                     Wx_f, b_f, Wx_b, b_b, gx_f, gx_b);
  hipLaunchKernelGGL(k2_lstm, dim3(32), dim3(64), 0, stream,
                     char_ids, gx_f, gx_b, Wh_f, Wh_b, sent);
  hipLaunchKernelGGL(k3_token, dim3(4096), dim3(64), 0, stream,
                     entity_ids, ent_table, sent, We, be, Wu, bu, Wv, bv,
                     W1, W2, ent_logits, Ap, Cp);
  hipLaunchKernelGGL(k4_rel, dim3(65536), dim3(256), 0, stream, Ap, Cp, biasp, rel);
}

// Round 3
// 153.471 us; speedup vs baseline: 1.0734x; 1.0734x over previous
//
#include <hip/hip_runtime.h>
#include <hip/hip_bf16.h>

#define Bb 16
#define Ll 256
#define EMBd 128
#define Hh 10
#define G4 40
#define ENTN 30
#define ENCd 84

typedef float f32x4 __attribute__((ext_vector_type(4)));

__device__ __forceinline__ float ex2(float x){ return __builtin_amdgcn_exp2f(x); }
__device__ __forceinline__ float frcp(float x){ return __builtin_amdgcn_rcpf(x); }
#define LOG2E 1.4426950408889634f
__device__ __forceinline__ float sigf(float x){ return frcp(1.f + ex2(-LOG2E*x)); }
__device__ __forceinline__ float tanhf_fast(float x){ return 1.f - 2.f*frcp(1.f + ex2(2.f*LOG2E*x)); }

// K01: fused. Blocks [0,4096): embed + gates_x (both dirs). Blocks [4096,4162): W1/W2/biasp precompute.
__global__ __launch_bounds__(128) void k01_embed_gates_weights(
    const int* __restrict__ char_ids, const int* __restrict__ word_ids,
    const float* __restrict__ char_table, const float* __restrict__ word_table,
    const float* __restrict__ Wx_f, const float* __restrict__ b_f,
    const float* __restrict__ Wx_b, const float* __restrict__ b_b,
    const float* __restrict__ Wuv, const float* __restrict__ buv,
    const float* __restrict__ Wr,  const float* __restrict__ br,
    float* __restrict__ gx_f, float* __restrict__ gx_b,
    float* __restrict__ W1, float* __restrict__ W2, float* __restrict__ biasp) {
  __shared__ float e[256];
  if (blockIdx.x >= 4096) {
    int idx = (blockIdx.x - 4096)*128 + threadIdx.x;
    if (idx < 4096) {
      int r = idx >> 6, k = idx & 63;
      float acc = 0.f;
      #pragma unroll 8
      for (int s = 0; s < 64; ++s) acc = fmaf(Wuv[r*64+s], Wr[s*64+k], acc);
      W1[idx] = acc;
    } else if (idx < 8192) {
      int jj = idx - 4096; int r = jj >> 6, k = jj & 63;
      float acc = 0.f;
      #pragma unroll 8
      for (int s = 0; s < 64; ++s) acc = fmaf(Wuv[(64+r)*64+s], Wr[s*64+k], acc);
      W2[jj] = acc;
    } else if (idx < 8256) {
      int k = idx - 8192;
      float acc = br[k];
      #pragma unroll 8
      for (int s = 0; s < 64; ++s) acc = fmaf(buv[s], Wr[s*64+k], acc);
      biasp[k] = acc;
    }
    return;
  }
  int tok = blockIdx.x;             // b*L + t
  int b = tok >> 8, t = tok & 255;
  int tid = threadIdx.x;
  int cid = char_ids[tok];
  int wid = word_ids[tok];
  e[tid]       = char_table[cid*EMBd + tid];
  e[tid + 128] = word_table[wid*EMBd + tid];
  __syncthreads();
  if (tid < G4) {
    float acc = b_f[tid];
    #pragma unroll 8
    for (int k = 0; k < 256; ++k) acc = fmaf(e[k], Wx_f[k*G4 + tid], acc);
    gx_f[(t*Bb + b)*G4 + tid] = acc;
  } else if (tid >= 64 && tid < 64 + G4) {
    int u = tid - 64;
    float acc = b_b[u];
    #pragma unroll 8
    for (int k = 0; k < 256; ++k) acc = fmaf(e[k], Wx_b[k*G4 + u], acc);
    gx_b[((Ll-1-t)*Bb + b)*G4 + u] = acc;
  }
}

// K2: one wave per (batch, direction). Gate-per-lane: lane l<40 owns gate column l
// (gate g=l/10, unit j=l%10). Unified nonlinearity act = a + b*rcp(1+exp2(s*z)).
// Gates recombined via ds_bpermute; h broadcast via readlane.
__global__ __launch_bounds__(64) void k2_lstm(
    const int* __restrict__ char_ids,
    const float* __restrict__ gx_f, const float* __restrict__ gx_b,
    const float* __restrict__ Wh_f, const float* __restrict__ Wh_b,
    float* __restrict__ sent) {
  int bid = blockIdx.x;
  int dir = bid & 1, b = bid >> 1;
  int lane = threadIdx.x;
  int l = lane < G4 ? lane : 0;          // clamp idle lanes
  int g = (l >= 30) ? 3 : (l >= 20) ? 2 : (l >= 10) ? 1 : 0;
  int j = l - 10*g;
  const float* gx = dir ? gx_b : gx_f;
  const float* Wh = dir ? Wh_b : Wh_f;
  float w[Hh];
  #pragma unroll
  for (int k = 0; k < Hh; ++k) w[k] = Wh[k*G4 + l];
  float s_    = (g == 2) ? (2.f*LOG2E) : (-LOG2E);
  float a_    = (g == 2) ? 1.f : 0.f;
  float bcoef = (g == 2) ? -2.f : 1.f;
  float c = 0.f, h = 0.f;
  float hbc[Hh];
  #pragma unroll
  for (int k = 0; k < Hh; ++k) hbc[k] = 0.f;
  const int cbase = b*Ll;
  float gnext = gx[(0*Bb + b)*G4 + l];
  int ncid = char_ids[cbase + (dir ? Ll-1 : 0)];
  for (int t = 0; t < Ll; ++t) {
    float gxv = gnext;
    int cid = ncid;
    if (t < Ll-1) {
      gnext = gx[((t+1)*Bb + b)*G4 + l];
      ncid = char_ids[cbase + (dir ? (Ll-2-t) : (t+1))];
    }
    float z0 = gxv, z1 = 0.f;
    #pragma unroll
    for (int k = 0; k < Hh; k += 2) {
      z0 = fmaf(hbc[k],   w[k],   z0);
      z1 = fmaf(hbc[k+1], w[k+1], z1);
    }
    float z = z0 + z1;
    float tt  = frcp(1.f + ex2(s_*z));
    float act = fmaf(bcoef, tt, a_);
    int ib = __float_as_int(act);
    float iv = __int_as_float(__builtin_amdgcn_ds_bpermute((j       )*4, ib));
    float fv = __int_as_float(__builtin_amdgcn_ds_bpermute((Hh   + j)*4, ib));
    float gv = __int_as_float(__builtin_amdgcn_ds_bpermute((2*Hh + j)*4, ib));
    float ov = __int_as_float(__builtin_amdgcn_ds_bpermute((3*Hh + j)*4, ib));
    float cn = fmaf(fv, c, iv*gv);
    float hn = ov * tanhf_fast(cn);
    bool m = (cid != 0);
    c = m ? cn : c;
    h = m ? hn : h;
    int t_orig = dir ? (Ll-1-t) : t;
    if (lane < Hh) sent[(cbase + t_orig)*20 + dir*Hh + lane] = h;
    #pragma unroll
    for (int k = 0; k < Hh; ++k)
      hbc[k] = __uint_as_float(__builtin_amdgcn_readlane(__float_as_uint(h), k));
  }
}

// K3: 16 tokens per 256-thread block (4 waves x 4 tokens). Wu/Wv staged in LDS once.
__global__ __launch_bounds__(256) void k3_token(
    const int* __restrict__ entity_ids,
    const float* __restrict__ ent_table,
    const float* __restrict__ sent,
    const float* __restrict__ We, const float* __restrict__ be,
    const float* __restrict__ Wu, const float* __restrict__ bu,
    const float* __restrict__ Wv, const float* __restrict__ bv,
    const float* __restrict__ W1, const float* __restrict__ W2,
    float* __restrict__ ent_logits, float* __restrict__ Ap, float* __restrict__ Cp) {
  __shared__ float sWu[ENCd*64];
  __shared__ float sWv[ENCd*64];
  __shared__ float encs[4][ENCd];
  __shared__ float sus[4][64];
  __shared__ float svs[4][64];
  int tid = threadIdx.x;
  for (int idx = tid; idx < ENCd*64; idx += 256) {
    sWu[idx] = Wu[idx];
    sWv[idx] = Wv[idx];
  }
  int wave = tid >> 6, lane = tid & 63;
  int tok0 = blockIdx.x * 16 + wave * 4;
  float bu_l = bu[lane], bv_l = bv[lane];
  __syncthreads();
  for (int it = 0; it < 4; ++it) {
    int tok = tok0 + it;
    int eid = entity_ids[tok];
    if (lane < 20) encs[wave][lane] = sent[tok*20 + lane];
    encs[wave][20 + lane] = ent_table[eid*64 + lane];
    __syncthreads();
    float a = bu_l, v = bv_l;
    #pragma unroll 4
    for (int k = 0; k < ENCd; ++k) {
      float ek = encs[wave][k];
      a = fmaf(ek, sWu[k*64 + lane], a);
      v = fmaf(ek, sWv[k*64 + lane], v);
    }
    a = fmaxf(a, 0.f); v = fmaxf(v, 0.f);
    sus[wave][lane] = a; svs[wave][lane] = v;
    if (lane < ENTN) {
      float el = be[lane];
      #pragma unroll
      for (int k = 0; k < 20; ++k) el = fmaf(encs[wave][k], We[k*ENTN + lane], el);
      ent_logits[tok*ENTN + lane] = el;
    }
    __syncthreads();
    float accA = 0.f, accC = 0.f;
    #pragma unroll 8
    for (int r = 0; r < 64; ++r) {
      accA = fmaf(sus[wave][r], W1[r*64 + lane], accA);
      accC = fmaf(svs[wave][r], W2[r*64 + lane], accC);
    }
    Ap[tok*64 + lane] = accA;
    Cp[tok*64 + lane] = accC;
    __syncthreads();
  }
}

// K4: rel_logits[b,i,j,:] = softmax_k(A'[b,j,k] + C'[b,i,k] + biasp[k])
// 16 rows per 256-thread block; 16 lanes x float4 per row; nontemporal stores.
__global__ __launch_bounds__(256) void k4_rel(
    const float* __restrict__ Ap, const float* __restrict__ Cp,
    const float* __restrict__ biasp, float* __restrict__ rel) {
  int tid = threadIdx.x;
  int rowLocal = tid >> 4;
  int k4 = tid & 15;
  int row = blockIdx.x*16 + rowLocal;      // b*L*L + i*L + j, < 2^20
  int b  = row >> 16;
  int ij = row & 65535;
  int i  = ij >> 8, j = ij & 255;
  const f32x4 a4 = *(const f32x4*)(Ap + ((size_t)(b*Ll + j))*64 + k4*4);
  const f32x4 c4 = *(const f32x4*)(Cp + ((size_t)(b*Ll + i))*64 + k4*4);
  const f32x4 bb = *(const f32x4*)(biasp + k4*4);
  float x0 = a4.x + c4.x + bb.x;
  float x1 = a4.y + c4.y + bb.y;
  float x2 = a4.z + c4.z + bb.z;
  float x3 = a4.w + c4.w + bb.w;
  float m = fmaxf(fmaxf(x0, x1), fmaxf(x2, x3));
  #pragma unroll
  for (int s = 1; s < 16; s <<= 1) m = fmaxf(m, __shfl_xor(m, s));
  float e0 = ex2(LOG2E*(x0 - m));
  float e1 = ex2(LOG2E*(x1 - m));
  float e2 = ex2(LOG2E*(x2 - m));
  float e3 = ex2(LOG2E*(x3 - m));
  float ssum = (e0 + e1) + (e2 + e3);
  #pragma unroll
  for (int s = 1; s < 16; s <<= 1) ssum += __shfl_xor(ssum, s);
  float rs = frcp(ssum);
  f32x4 o; o.x = e0*rs; o.y = e1*rs; o.z = e2*rs; o.w = e3*rs;
  __builtin_nontemporal_store(o, (f32x4*)(rel + (size_t)row*64 + k4*4));
}

extern "C" void kernel_launch(void* const* d_in, const int* in_sizes, int n_in,
                              void* d_out, int out_size, void* d_ws, size_t ws_size,
                              hipStream_t stream) {
  const int*   char_ids   = (const int*)  d_in[0];
  const int*   word_ids   = (const int*)  d_in[1];
  const int*   entity_ids = (const int*)  d_in[2];
  const float* char_table = (const float*)d_in[3];
  const float* word_table = (const float*)d_in[4];
  const float* ent_table  = (const float*)d_in[5];
  const float* Wx_f = (const float*)d_in[6];
  const float* Wh_f = (const float*)d_in[7];
  const float* b_f  = (const float*)d_in[8];
  const float* Wx_b = (const float*)d_in[9];
  const float* Wh_b = (const float*)d_in[10];
  const float* b_b  = (const float*)d_in[11];
  const float* We = (const float*)d_in[12];
  const float* be = (const float*)d_in[13];
  const float* Wu = (const float*)d_in[14];
  const float* bu = (const float*)d_in[15];
  const float* Wv = (const float*)d_in[16];
  const float* bv = (const float*)d_in[17];
  const float* Wuv = (const float*)d_in[18];
  const float* buv = (const float*)d_in[19];
  const float* Wr  = (const float*)d_in[20];
  const float* br  = (const float*)d_in[21];

  float* ws   = (float*)d_ws;
  float* gx_f = ws;                  // 256*16*40 = 163840
  float* gx_b = gx_f + 163840;       // 163840
  float* sent = gx_b + 163840;       // 16*256*20 = 81920
  float* W1   = sent + 81920;        // 4096
  float* W2   = W1 + 4096;           // 4096
  float* biasp= W2 + 4096;           // 64
  float* Ap   = biasp + 64;          // 16*256*64 = 262144
  float* Cp   = Ap + 262144;         // 262144

  float* out = (float*)d_out;
  float* ent_logits = out;           // 16*256*30 = 122880
  float* rel = out + 122880;         // 16*256*256*64

  hipLaunchKernelGGL(k01_embed_gates_weights, dim3(4162), dim3(128), 0, stream,
                     char_ids, word_ids, char_table, word_table,
                     Wx_f, b_f, Wx_b, b_b, Wuv, buv, Wr, br,
                     gx_f, gx_b, W1, W2, biasp);
  hipLaunchKernelGGL(k2_lstm, dim3(32), dim3(64), 0, stream,
                     char_ids, gx_f, gx_b, Wh_f, Wh_b, sent);
  hipLaunchKernelGGL(k3_token, dim3(256), dim3(256), 0, stream,
                     entity_ids, ent_table, sent, We, be, Wu, bu, Wv, bv,
                     W1, W2, ent_logits, Ap, Cp);
  hipLaunchKernelGGL(k4_rel, dim3(65536), dim3(256), 0, stream, Ap, Cp, biasp, rel);
}